// Round 1
// baseline (226.556 us; speedup 1.0000x reference)
//
#include <hip/hip_runtime.h>
#include <hip/hip_bf16.h>

// Problem constants (fixed by setup_inputs)
#define B_N 4096
#define D_K 512
#define INV_T 10.0f

// ws layout:
//   [0, 16384)        : float denom[4096]
//   [16384, 16392)    : float acc[2] = {loss_sum, num_pos}
//   [32768, +4MiB)    : bf16 copy of embeddings [4096][512]

typedef __attribute__((ext_vector_type(8))) short short8;   // bf16x8 MFMA frag
typedef __attribute__((ext_vector_type(4))) float float4v;  // f32x4 accumulator

static __device__ inline unsigned short f32_to_bf16_rne(float f) {
    unsigned int u = __float_as_uint(f);
    unsigned int lsb = (u >> 16) & 1u;
    u += 0x7fffu + lsb;
    return (unsigned short)(u >> 16);
}

static __device__ inline float bf16_to_f32(unsigned short h) {
    unsigned int u = ((unsigned int)h) << 16;
    return __uint_as_float(u);
}

// ---------------- k0: fp32 -> bf16 convert + zero accumulators ----------------
__global__ __launch_bounds__(256) void k0_convert(const float* __restrict__ emb,
                                                  unsigned short* __restrict__ embB,
                                                  float* __restrict__ denom,
                                                  float* __restrict__ acc) {
    int tid = blockIdx.x * blockDim.x + threadIdx.x;
    int base = tid * 4;
    if (base < B_N * D_K) {
        float4 v = *(const float4*)(emb + base);
        ushort4 o;
        o.x = f32_to_bf16_rne(v.x);
        o.y = f32_to_bf16_rne(v.y);
        o.z = f32_to_bf16_rne(v.z);
        o.w = f32_to_bf16_rne(v.w);
        *(ushort4*)(embB + base) = o;
    }
    if (tid < B_N) denom[tid] = 0.0f;
    if (tid == 0) { acc[0] = 0.0f; acc[1] = 0.0f; }
}

// ---------------- k1: fused denom[i] = sum_j(neg) exp(10*dot(E_i,E_j)) -------
// Block: 256 threads = 4 waves. Each wave owns 16 rows; block owns 64 rows x
// 512 columns (8-way column split across blockIdx.y). A-fragments held in
// registers for the whole column loop; B-tile (16 cols x 512 k) staged in LDS.
#define RM 64
#define CPB 512
#define CS (B_N / CPB)

__global__ __launch_bounds__(256) void k1_denom(const unsigned short* __restrict__ embB,
                                                const int* __restrict__ labels,
                                                float* __restrict__ denom) {
    __shared__ unsigned short sB[16][520];  // +8 pad: breaks 16-way b128 bank conflict

    const int tid  = threadIdx.x;
    const int wave = tid >> 6;
    const int lane = tid & 63;
    const int quad = lane >> 4;
    const int l16  = lane & 15;

    const int rowBase  = blockIdx.x * RM + wave * 16;
    const int colBase0 = blockIdx.y * CPB;

    // A fragments: row = rowBase + l16, k = kc*32 + quad*8 .. +8 (contiguous 16B)
    short8 afrag[16];
    {
        const unsigned short* ap = embB + (rowBase + l16) * D_K + quad * 8;
#pragma unroll
        for (int kc = 0; kc < 16; ++kc)
            afrag[kc] = *(const short8*)(ap + kc * 32);
    }

    // labels for my 4 output rows (row = quad*4 + r)
    int labI[4];
#pragma unroll
    for (int r = 0; r < 4; ++r) labI[r] = labels[rowBase + quad * 4 + r];

    float rowAcc[4] = {0.0f, 0.0f, 0.0f, 0.0f};

    for (int jt = 0; jt < CPB / 16; ++jt) {
        const int colBase = colBase0 + jt * 16;

        __syncthreads();  // protect sB reads of previous iteration
        // stage 16 cols x 512 k (8192 bf16) : 256 threads x 16B x 4 passes
#pragma unroll
        for (int p = 0; p < 4; ++p) {
            int li = (p * 256 + tid) * 8;
            int c  = li >> 9;
            int k  = li & 511;
            *(short8*)(&sB[c][k]) = *(const short8*)(embB + (colBase + c) * D_K + k);
        }
        __syncthreads();

        float4v acc = {0.0f, 0.0f, 0.0f, 0.0f};
#pragma unroll
        for (int kc = 0; kc < 16; ++kc) {
            short8 bfrag = *(const short8*)(&sB[l16][kc * 32 + quad * 8]);
            acc = __builtin_amdgcn_mfma_f32_16x16x32_bf16(afrag[kc], bfrag, acc, 0, 0, 0);
        }

        const int labJ = labels[colBase + l16];
#pragma unroll
        for (int r = 0; r < 4; ++r) {
            float s = acc[r] * INV_T;
            float e = (labJ != labI[r]) ? __expf(s) : 0.0f;
            rowAcc[r] += e;
        }
    }

    // butterfly over the 16 lanes sharing this quad (sums over all block cols)
#pragma unroll
    for (int r = 0; r < 4; ++r) {
        float v = rowAcc[r];
        v += __shfl_xor(v, 1);
        v += __shfl_xor(v, 2);
        v += __shfl_xor(v, 4);
        v += __shfl_xor(v, 8);
        if (l16 == 0) atomicAdd(&denom[rowBase + quad * 4 + r], v);
    }
}

// ---------------- k2: positive-pair terms --------------------------------
// One block per row i. Collect same-label j's into LDS list, then each wave
// processes matches round-robin: dot from (fp32 LDS E_i) x (bf16 global E_j).
__global__ __launch_bounds__(256) void k2_pos(const float* __restrict__ emb,
                                              const unsigned short* __restrict__ embB,
                                              const int* __restrict__ labels,
                                              const float* __restrict__ denom,
                                              float* __restrict__ acc) {
    __shared__ float sEi[D_K];
    __shared__ int   sList[4096];
    __shared__ int   sCount;
    __shared__ float sSum;

    const int i   = blockIdx.x;
    const int tid = threadIdx.x;
    if (tid == 0) { sCount = 0; sSum = 0.0f; }
    for (int e = tid; e < D_K; e += 256) sEi[e] = emb[i * D_K + e];
    const int labI = labels[i];
    __syncthreads();

    for (int j = tid; j < B_N; j += 256) {
        if (j != i && labels[j] == labI) {
            int p = atomicAdd(&sCount, 1);
            sList[p] = j;
        }
    }
    __syncthreads();

    const int cnt  = sCount;
    const int wave = tid >> 6;
    const int lane = tid & 63;
    const float dnm = denom[i];

    float wsum = 0.0f;
    for (int m = wave; m < cnt; m += 4) {
        const int j = sList[m];
        const unsigned short* pj = embB + j * D_K;
        float d = 0.0f;
#pragma unroll
        for (int e = 0; e < 8; ++e)
            d += sEi[e * 64 + lane] * bf16_to_f32(pj[e * 64 + lane]);
        for (int off = 32; off; off >>= 1) d += __shfl_xor(d, off);
        if (lane == 0) {
            float s  = d * INV_T;
            float es = __expf(s);
            wsum += logf(dnm + es) - s;
        }
    }
    if (lane == 0) atomicAdd(&sSum, wsum);
    __syncthreads();
    if (tid == 0) {
        atomicAdd(&acc[0], sSum);
        atomicAdd(&acc[1], (float)cnt);
    }
}

// ---------------- k3: final divide ----------------------------------------
__global__ void k3_final(const float* __restrict__ acc, float* __restrict__ out) {
    out[0] = acc[0] / fmaxf(acc[1], 1.0f);
}

extern "C" void kernel_launch(void* const* d_in, const int* in_sizes, int n_in,
                              void* d_out, int out_size, void* d_ws, size_t ws_size,
                              hipStream_t stream) {
    const float* emb    = (const float*)d_in[0];
    const int*   labels = (const int*)d_in[1];
    float*       out    = (float*)d_out;

    char* ws = (char*)d_ws;
    float*          denom = (float*)ws;
    float*          acc   = (float*)(ws + 16384);
    unsigned short* embB  = (unsigned short*)(ws + 32768);

    k0_convert<<<dim3((B_N * D_K / 4 + 255) / 256), dim3(256), 0, stream>>>(emb, embB, denom, acc);

    dim3 g1(B_N / RM, CS);
    k1_denom<<<g1, dim3(256), 0, stream>>>(embB, labels, denom);

    k2_pos<<<dim3(B_N), dim3(256), 0, stream>>>(emb, embB, labels, denom, acc);

    k3_final<<<dim3(1), dim3(1), 0, stream>>>(acc, out);
}